// Round 2
// baseline (1093.852 us; speedup 1.0000x reference)
//
#include <hip/hip_runtime.h>
#include <hip/hip_bf16.h>
#include <math.h>

#define NRL   4
#define WD    64
#define NB    64
#define LL    4096
#define NFFT  4104      // L + PAD
#define LP    4224      // padded stride: 33*128, zero tail beyond NFFT
#define LP4   (LP/4)
#define NROWS (NB*WD)   // 4096

__device__ inline float gelu_f(float v){
  return 0.5f*v*(1.0f + erff(v*0.70710678118654752440f));
}

// Build trig tables.
// tfr/tfi: forward DFT, layout [l/4][m][l%4]  (float4 per (m, l-quad), coalesced over m)
// ti: inverse table, [j][LP] row-major, j=2m -> scaled cos, j=2m+1 -> scaled -sin
__global__ void k_trig(float* __restrict__ tfr, float* __restrict__ tfi,
                       float* __restrict__ ti) {
  int idx = blockIdx.x*blockDim.x + threadIdx.x;
  if (idx >= 32*LP) return;
  int m = idx / LP, l = idx - m*LP;
  float c = 0.f, s = 0.f;
  if (l < NFFT) {
    int r = (m*l) % NFFT;
    float ang = 6.28318530717958647692f * ((float)r / (float)NFFT);
    sincosf(ang, &s, &c);
  }
  int tri = (l >> 2)*128 + m*4 + (l & 3);
  tfr[tri] = c;
  tfi[tri] = s;
  const float inv = 1.0f / (float)NFFT;
  ti[(size_t)(2*m)*LP + l]   = (m == 0 ? inv : 2.f*inv) * c;
  ti[(size_t)(2*m+1)*LP + l] = (m == 0 ? 0.f : -2.f*inv*s);
}

// lift: x(B,1,L) + grid -> xb(NROWS, LP) fp32, zero tail l>=LL
__global__ void k_lift(const float* __restrict__ x, const float* __restrict__ lw,
                       const float* __restrict__ lb, float* __restrict__ xb) {
  int idx = blockIdx.x*blockDim.x + threadIdx.x;
  if (idx >= NROWS*LP4) return;
  int l4 = idx % LP4, row = idx / LP4;
  int b = row >> 6, c = row & 63;
  int l = l4 << 2;
  float4 o = make_float4(0.f,0.f,0.f,0.f);
  if (l < LL) {
    const float4 xv = *reinterpret_cast<const float4*>(x + (size_t)b*LL + l);
    float w0 = lw[2*c], w1 = lw[2*c+1], bb = lb[c];
    const float gs = 1.0f/4095.0f;
    o.x = fmaf(w1, (float)(l+0)*gs, fmaf(w0, xv.x, bb));
    o.y = fmaf(w1, (float)(l+1)*gs, fmaf(w0, xv.y, bb));
    o.z = fmaf(w1, (float)(l+2)*gs, fmaf(w0, xv.z, bb));
    o.w = fmaf(w1, (float)(l+3)*gs, fmaf(w0, xv.w, bb));
  }
  *reinterpret_cast<float4*>(xb + (size_t)row*LP + l) = o;
}

__global__ void k_zero(float* __restrict__ p, int n){
  int i = blockIdx.x*blockDim.x + threadIdx.x;
  if (i < n) p[i] = 0.f;
}

// Forward 32-mode DFT: xm[row][2m]+=sum_l x*cos, [2m+1]-=sum_l x*sin
// block: 256 thr = 8 rowgroups x 32 modes; thread owns 8 rows, 1 mode, 528 l's
__global__ __launch_bounds__(256) void k_dft(const float* __restrict__ xb,
    const float* __restrict__ tfr, const float* __restrict__ tfi,
    float* __restrict__ xm) {
  int m  = threadIdx.x & 31;
  int rg = threadIdx.x >> 5;
  int r0 = blockIdx.x*64 + rg*8;
  int lbase = blockIdx.y*528;
  const float* xp = xb + (size_t)r0*LP + lbase;
  const float* cp = tfr + (size_t)(lbase >> 2)*128 + m*4;
  const float* sp = tfi + (size_t)(lbase >> 2)*128 + m*4;
  float re[8], im[8];
  #pragma unroll
  for (int j=0;j<8;j++){ re[j]=0.f; im[j]=0.f; }
  for (int i=0;i<132;i++){
    float4 c4 = *reinterpret_cast<const float4*>(cp + (size_t)i*128);
    float4 s4 = *reinterpret_cast<const float4*>(sp + (size_t)i*128);
    #pragma unroll
    for (int j=0;j<8;j++){
      float4 xv = *reinterpret_cast<const float4*>(xp + (size_t)j*LP + i*4);
      re[j] = fmaf(xv.x, c4.x, re[j]); re[j] = fmaf(xv.y, c4.y, re[j]);
      re[j] = fmaf(xv.z, c4.z, re[j]); re[j] = fmaf(xv.w, c4.w, re[j]);
      im[j] = fmaf(xv.x, s4.x, im[j]); im[j] = fmaf(xv.y, s4.y, im[j]);
      im[j] = fmaf(xv.z, s4.z, im[j]); im[j] = fmaf(xv.w, s4.w, im[j]);
    }
  }
  #pragma unroll
  for (int j=0;j<8;j++){
    atomicAdd(&xm[(size_t)(r0+j)*64 + 2*m],     re[j]);
    atomicAdd(&xm[(size_t)(r0+j)*64 + 2*m + 1], -im[j]);
  }
}

// complex mode mix: om[b][o][2m(+1)] = sum_i Xm[b][i][m] * (wr+i*wi)[i][o][m]
__global__ void k_mix(const float* __restrict__ xm, const float* __restrict__ wr,
                      const float* __restrict__ wi, float* __restrict__ om) {
  int idx = blockIdx.x*blockDim.x + threadIdx.x;   // 131072 = 64b*64o*32m
  int m = idx & 31, o = (idx >> 5) & 63, b = idx >> 11;
  const float* xp = xm + (size_t)b*4096 + 2*m;
  float ar = 0.f, ai = 0.f;
  for (int i=0;i<64;i++){
    float xr = xp[i*64], xi = xp[i*64+1];
    float wrv = wr[((size_t)i*64 + o)*32 + m];
    float wiv = wi[((size_t)i*64 + o)*32 + m];
    ar += xr*wrv - xi*wiv;
    ai += xr*wiv + xi*wrv;
  }
  om[((size_t)b*64 + o)*64 + 2*m]   = ar;
  om[((size_t)b*64 + o)*64 + 2*m+1] = ai;
}

// fused pointwise conv + inverse spectral + bias (+gelu) per layer
// block: 256 thr = 8 o-groups(8 o each) x 32 l-groups(4 l each); covers 64 o x 128 l of batch b
__global__ __launch_bounds__(256) void k_layer(const float* __restrict__ xb,
    const float* __restrict__ ti, const float* __restrict__ om,
    const float* __restrict__ cw, const float* __restrict__ cb,
    float* __restrict__ xout, float* __restrict__ yout, int last) {
  int lg = threadIdx.x & 31, og = threadIdx.x >> 5;
  int b = blockIdx.y;
  int l = blockIdx.x*128 + lg*4;
  int o0 = og*8;
  float4 acc[8];
  #pragma unroll
  for (int j=0;j<8;j++) acc[j] = make_float4(0.f,0.f,0.f,0.f);

  const float* xp = xb + (size_t)b*64*LP + l;
  for (int c=0;c<64;c++){
    float4 xv = *reinterpret_cast<const float4*>(xp); xp += LP;
    #pragma unroll
    for (int j=0;j<8;j++){
      float wv = cw[(o0+j)*64 + c];
      acc[j].x = fmaf(wv, xv.x, acc[j].x);
      acc[j].y = fmaf(wv, xv.y, acc[j].y);
      acc[j].z = fmaf(wv, xv.z, acc[j].z);
      acc[j].w = fmaf(wv, xv.w, acc[j].w);
    }
  }
  const float* tp = ti + l;
  const float* op = om + ((size_t)b*64 + o0)*64;
  for (int j2=0;j2<64;j2++){
    float4 tv = *reinterpret_cast<const float4*>(tp); tp += LP;
    #pragma unroll
    for (int j=0;j<8;j++){
      float ov = op[j*64 + j2];
      acc[j].x = fmaf(ov, tv.x, acc[j].x);
      acc[j].y = fmaf(ov, tv.y, acc[j].y);
      acc[j].z = fmaf(ov, tv.z, acc[j].z);
      acc[j].w = fmaf(ov, tv.w, acc[j].w);
    }
  }
  if (!last) {
    #pragma unroll
    for (int j=0;j<8;j++){
      float4 v = make_float4(0.f,0.f,0.f,0.f);
      if (l < NFFT) {
        float bb = cb[o0+j];
        v.x = gelu_f(acc[j].x + bb);
        v.y = gelu_f(acc[j].y + bb);
        v.z = gelu_f(acc[j].z + bb);
        v.w = gelu_f(acc[j].w + bb);
      }
      *reinterpret_cast<float4*>(xout + ((size_t)b*64 + o0 + j)*LP + l) = v;
    }
  } else {
    if (l < LL) {
      #pragma unroll
      for (int j=0;j<8;j++){
        float bb = cb[o0+j];
        float4 v;
        v.x = acc[j].x + bb;
        v.y = acc[j].y + bb;
        v.z = acc[j].z + bb;
        v.w = acc[j].w + bb;
        *reinterpret_cast<float4*>(yout + ((size_t)(b*64 + o0 + j))*LL + l) = v;
      }
    }
  }
}

extern "C" void kernel_launch(void* const* d_in, const int* in_sizes, int n_in,
                              void* d_out, int out_size, void* d_ws, size_t ws_size,
                              hipStream_t stream) {
  const float* x   = (const float*)d_in[0];
  const float* lw  = (const float*)d_in[1];
  const float* lb  = (const float*)d_in[2];
  const float* cw  = (const float*)d_in[3];
  const float* cb  = (const float*)d_in[4];
  const float* swr = (const float*)d_in[5];
  const float* swi = (const float*)d_in[6];

  // workspace layout (floats); total ~142.7 MB
  float* ws  = (float*)d_ws;
  float* xb0 = ws;
  float* xb1 = xb0 + (size_t)NROWS*LP;
  float* tfr = xb1 + (size_t)NROWS*LP;
  float* tfi = tfr + (size_t)32*LP;
  float* ti  = tfi + (size_t)32*LP;
  float* xm  = ti  + (size_t)64*LP;
  float* om  = xm  + (size_t)NROWS*64;

  k_trig<<<(32*LP + 255)/256, 256, 0, stream>>>(tfr, tfi, ti);
  k_lift<<<(NROWS*LP4 + 255)/256, 256, 0, stream>>>(x, lw, lb, xb0);

  float* cur = xb0;
  float* nxt = xb1;
  for (int k=0;k<NRL;k++){
    k_zero<<<(NROWS*64 + 255)/256, 256, 0, stream>>>(xm, NROWS*64);
    k_dft<<<dim3(NROWS/64, 8), 256, 0, stream>>>(cur, tfr, tfi, xm);
    k_mix<<<(NROWS*32)/256, 256, 0, stream>>>(xm, swr + (size_t)k*64*64*32,
                                              swi + (size_t)k*64*64*32, om);
    k_layer<<<dim3(LP/128, NB), 256, 0, stream>>>(cur, ti, om,
        cw + (size_t)k*64*64, cb + (size_t)k*64,
        nxt, (float*)d_out, (k == NRL-1) ? 1 : 0);
    float* t = cur; cur = nxt; nxt = t;
  }
}

// Round 3
// 365.883 us; speedup vs baseline: 2.9896x; 2.9896x over previous
//
#include <hip/hip_runtime.h>
#include <hip/hip_bf16.h>
#include <math.h>

#define NRL 4
#define LL 4096
#define NFFT 4104
#define LP 4224
#define NB 64
#define WD 64
#define BST (LP*WD*2)        // 540672 bytes per batch per plane ([l][c] bf16)
#define DCH 12
#define DKS 11
#define PI2 6.28318530717958647692f

typedef __attribute__((ext_vector_type(8))) short short8;
typedef __attribute__((ext_vector_type(4))) float f32x4;

__device__ inline unsigned short f2bf(float f){
  unsigned int u = __float_as_uint(f);
  return (unsigned short)((u + 0x7FFFu + ((u>>16)&1u)) >> 16);
}
__device__ inline float gelu_f(float v){
  return 0.5f*v*(1.0f + erff(v*0.70710678118654752440f));
}

// ---- forward-DFT B-operand table, fragment order: tf[ks 132][js 4][lane 64][e 8]
__global__ void k_tf(unsigned short* __restrict__ tf){
  int idx = blockIdx.x*256 + threadIdx.x;     // 270336
  int e = idx & 7; int t = idx >> 3;
  int lane = t & 63; int t2 = t >> 6;
  int js = t2 & 3; int ks = t2 >> 2;
  int l = ks*32 + 8*(lane>>4) + e;
  int j = js*16 + (lane & 15);
  int m = j >> 1;
  float v = 0.f;
  if (l < NFFT){
    int r = (m*l) % NFFT;
    float ang = PI2 * ((float)r / (float)NFFT);
    v = (j & 1) ? -sinf(ang) : cosf(ang);
  }
  tf[idx] = f2bf(v);
}

// ---- inverse-spectral B-operand table: tif[(ks2*4+q)*LP + l][e 8]
__global__ void k_tif(unsigned short* __restrict__ tif){
  int idx = blockIdx.x*256 + threadIdx.x;     // 270336
  int e = idx & 7; int t = idx >> 3;
  int l = t % LP; int rq = t / LP;
  int q = rq & 3; int ks2 = rq >> 2;
  int j2 = ks2*32 + 8*q + e;
  int m = j2 >> 1;
  float v = 0.f;
  if (l < NFFT){
    int r = (m*l) % NFFT;
    float ang = PI2 * ((float)r / (float)NFFT);
    float inv = 1.0f/(float)NFFT;
    v = (j2 & 1) ? (-2.f*inv*sinf(ang)) : ((m==0?inv:2.f*inv)*cosf(ang));
  }
  tif[idx] = f2bf(v);
}

// ---- conv-weight A-operand frags: [layer 4][ks2 2][os 4][lane 64][e 8] hi/lo
__global__ void k_wfc(const float* __restrict__ cw,
                      unsigned short* __restrict__ whi, unsigned short* __restrict__ wlo){
  int idx = blockIdx.x*256 + threadIdx.x;     // 16384
  int e = idx & 7; int lane = (idx>>3)&63; int os = (idx>>9)&3;
  int ks2 = (idx>>11)&1; int ly = idx>>12;
  int k = ks2*32 + 8*(lane>>4) + e;
  int o = os*16 + (lane&15);
  float v = cw[((size_t)(ly*64 + o))*64 + k];
  unsigned short h = f2bf(v);
  float lo = v - __uint_as_float(((unsigned)h)<<16);
  whi[idx] = h; wlo[idx] = f2bf(lo);
}

// ---- lift: one thread per (b,l), writes swizzled [l][c] hi/lo rows
__global__ void k_lift(const float* __restrict__ x, const float* __restrict__ lw,
                       const float* __restrict__ lb,
                       unsigned short* __restrict__ xh, unsigned short* __restrict__ xl){
  int idx = blockIdx.x*256 + threadIdx.x;     // 270336
  int l = idx % LP; int b = idx / LP;
  char* ph = (char*)xh + (size_t)b*BST + (size_t)l*128;
  char* pl = (char*)xl + (size_t)b*BST + (size_t)l*128;
  int sw = (l & 7) << 4;
  if (l >= LL){
    uint4 z = make_uint4(0,0,0,0);
    #pragma unroll
    for (int u=0;u<8;u++){
      *(uint4*)(ph + ((u*16)^sw)) = z;
      *(uint4*)(pl + ((u*16)^sw)) = z;
    }
    return;
  }
  float xv = x[(size_t)b*LL + l];
  float g = (float)l * (1.0f/4095.0f);
  #pragma unroll
  for (int u=0;u<8;u++){
    unsigned int hw_[4], lw_[4];
    #pragma unroll
    for (int p=0;p<4;p++){
      unsigned int hh=0, llw=0;
      #pragma unroll
      for (int s=0;s<2;s++){
        int c = u*8 + p*2 + s;
        float v = fmaf(lw[2*c], xv, fmaf(lw[2*c+1], g, lb[c]));
        unsigned short h = f2bf(v);
        float lo = v - __uint_as_float(((unsigned)h)<<16);
        hh  |= ((unsigned)h) << (16*s);
        llw |= ((unsigned)f2bf(lo)) << (16*s);
      }
      hw_[p]=hh; lw_[p]=llw;
    }
    *(uint4*)(ph + ((u*16)^sw)) = make_uint4(hw_[0],hw_[1],hw_[2],hw_[3]);
    *(uint4*)(pl + ((u*16)^sw)) = make_uint4(lw_[0],lw_[1],lw_[2],lw_[3]);
  }
}

// ---- forward DFT via MFMA: D[c][j] partials per (chunk,b). No atomics.
__global__ __launch_bounds__(256) void k_dft(const unsigned short* __restrict__ xh,
    const unsigned short* __restrict__ tf, float* __restrict__ xmp){
  int ch = blockIdx.x; int b = blockIdx.y;
  int w = threadIdx.x >> 6; int lane = threadIdx.x & 63;
  int q = lane >> 4; int lr = lane & 15;
  int c = w*16 + lr;
  f32x4 acc[4];
  #pragma unroll
  for (int js=0;js<4;js++) acc[js] = (f32x4){0.f,0.f,0.f,0.f};
  const char* xbase = (const char*)xh + (size_t)b*BST;
  for (int ksl=0; ksl<DKS; ksl++){
    int ks = ch*DKS + ksl;
    int lb_ = ks*32 + 8*q;
    short8 av;
    #pragma unroll
    for (int e=0;e<8;e++){
      int l = lb_ + e;
      av[e] = *(const short*)(xbase + (size_t)l*128 + ((c*2)^((l&7)<<4)));
    }
    #pragma unroll
    for (int js=0;js<4;js++){
      short8 bv = *(const short8*)(tf + ((size_t)((ks*4+js)*64 + lane))*8);
      acc[js] = __builtin_amdgcn_mfma_f32_16x16x32_bf16(av, bv, acc[js], 0,0,0);
    }
  }
  #pragma unroll
  for (int js=0;js<4;js++){
    #pragma unroll
    for (int r=0;r<4;r++)
      xmp[(size_t)ch*262144 + ((size_t)(b*64 + w*16 + 4*q + r))*64 + js*16 + lr] = acc[js][r];
  }
}

__global__ void k_red(const float* __restrict__ xmp, float* __restrict__ xm){
  int i = blockIdx.x*256 + threadIdx.x;       // 262144
  float s = 0.f;
  #pragma unroll
  for (int p=0;p<DCH;p++) s += xmp[(size_t)p*262144 + i];
  xm[i] = s;
}

// ---- mode mix -> om A-operand frags [b][ks2 2][os 4][lane 64][e 8] hi/lo
__global__ void k_mix(const float* __restrict__ xm, const float* __restrict__ wr,
                      const float* __restrict__ wi,
                      unsigned short* __restrict__ mh, unsigned short* __restrict__ ml){
  int idx = blockIdx.x*256 + threadIdx.x;     // 131072
  int m = idx & 31, o = (idx>>5)&63, b = idx>>11;
  const float* xp = xm + ((size_t)(b*64))*64 + 2*m;
  float ar=0.f, ai=0.f;
  for (int i=0;i<64;i++){
    float xr = xp[i*64], xi = xp[i*64+1];
    float wrv = wr[((size_t)(i*64 + o))*32 + m];
    float wiv = wi[((size_t)(i*64 + o))*32 + m];
    ar = fmaf(xr,wrv,ar); ar = fmaf(-xi,wiv,ar);
    ai = fmaf(xr,wiv,ai); ai = fmaf(xi,wrv,ai);
  }
  int j2 = 2*m;
  int ks2 = j2 >> 5, rem = j2 & 31, q = rem >> 3, e = rem & 7;
  int lane = q*16 + (o & 15), os = o >> 4;
  size_t a = ((size_t)(((b*2 + ks2)*4 + os)*64 + lane))*8 + e;
  unsigned short hr = f2bf(ar), hi_ = f2bf(ai);
  float lr_ = ar - __uint_as_float(((unsigned)hr)<<16);
  float li_ = ai - __uint_as_float(((unsigned)hi_)<<16);
  *(ushort2*)(mh + a) = make_ushort2(hr, hi_);
  *(ushort2*)(ml + a) = make_ushort2(f2bf(lr_), f2bf(li_));
}

// ---- fused layer: out[o][l] = conv + inverse spectral, MFMA, hi/lo split
__global__ __launch_bounds__(256) void k_layer(
    const unsigned short* __restrict__ xch, const unsigned short* __restrict__ xcl,
    const unsigned short* __restrict__ wfch, const unsigned short* __restrict__ wfcl,
    const unsigned short* __restrict__ wmh, const unsigned short* __restrict__ wml,
    const unsigned short* __restrict__ tif, const float* __restrict__ cb,
    unsigned short* __restrict__ xnh, unsigned short* __restrict__ xnl,
    float* __restrict__ dout, int last){
  __shared__ __align__(16) char smem[32768];
  int l0 = blockIdx.x * 128; int b = blockIdx.y;
  int tid = threadIdx.x;
  int w = tid >> 6, lane = tid & 63, q = lane >> 4, lr = lane & 15;
  {
    const uint4* gh = (const uint4*)((const char*)xch + (size_t)b*BST + (size_t)l0*128);
    const uint4* gl = (const uint4*)((const char*)xcl + (size_t)b*BST + (size_t)l0*128);
    uint4* sh = (uint4*)smem; uint4* sl = (uint4*)(smem + 16384);
    #pragma unroll
    for (int i=0;i<4;i++) sh[i*256 + tid] = gh[i*256 + tid];
    #pragma unroll
    for (int i=0;i<4;i++) sl[i*256 + tid] = gl[i*256 + tid];
  }
  __syncthreads();
  int os = w;
  short8 ch_[2], cl_[2], mh_[2], ml_[2];
  #pragma unroll
  for (int ks=0;ks<2;ks++){
    size_t a = ((size_t)((ks*4 + os)*64 + lane))*8;
    ch_[ks] = *(const short8*)(wfch + a);
    cl_[ks] = *(const short8*)(wfcl + a);
    size_t am = ((size_t)(((b*2 + ks)*4 + os)*64 + lane))*8;
    mh_[ks] = *(const short8*)(wmh + am);
    ml_[ks] = *(const short8*)(wml + am);
  }
  f32x4 acc[8];
  #pragma unroll
  for (int ls=0;ls<8;ls++) acc[ls] = (f32x4){0.f,0.f,0.f,0.f};
  int sw = (lr & 7) << 4;
  #pragma unroll
  for (int ks=0;ks<2;ks++){
    int cofs = (64*ks + 16*q) ^ sw;
    #pragma unroll
    for (int ls=0;ls<8;ls++){
      int lrow = ls*16 + lr;
      short8 bh = *(const short8*)(smem + lrow*128 + cofs);
      short8 bl = *(const short8*)(smem + 16384 + lrow*128 + cofs);
      acc[ls] = __builtin_amdgcn_mfma_f32_16x16x32_bf16(ch_[ks], bh, acc[ls], 0,0,0);
      acc[ls] = __builtin_amdgcn_mfma_f32_16x16x32_bf16(cl_[ks], bh, acc[ls], 0,0,0);
      acc[ls] = __builtin_amdgcn_mfma_f32_16x16x32_bf16(ch_[ks], bl, acc[ls], 0,0,0);
    }
  }
  #pragma unroll
  for (int ks=0;ks<2;ks++){
    #pragma unroll
    for (int ls=0;ls<8;ls++){
      int l = l0 + ls*16 + lr;
      short8 bt = *(const short8*)(tif + ((size_t)((ks*4 + q)*LP + l))*8);
      acc[ls] = __builtin_amdgcn_mfma_f32_16x16x32_bf16(mh_[ks], bt, acc[ls], 0,0,0);
      acc[ls] = __builtin_amdgcn_mfma_f32_16x16x32_bf16(ml_[ks], bt, acc[ls], 0,0,0);
    }
  }
  float bias[4];
  #pragma unroll
  for (int r=0;r<4;r++) bias[r] = cb[os*16 + 4*q + r];
  if (!last){
    int co = os*32 + 8*q;
    #pragma unroll
    for (int ls=0;ls<8;ls++){
      int l = l0 + ls*16 + lr;
      unsigned int h0=0,h1=0,lo0=0,lo1=0;
      #pragma unroll
      for (int r=0;r<4;r++){
        float v = gelu_f(acc[ls][r] + bias[r]);
        unsigned short h = f2bf(v);
        float lo = v - __uint_as_float(((unsigned)h)<<16);
        unsigned short lo16 = f2bf(lo);
        if (r<2){ h0 |= ((unsigned)h)<<(16*r);     lo0 |= ((unsigned)lo16)<<(16*r); }
        else    { h1 |= ((unsigned)h)<<(16*(r-2)); lo1 |= ((unsigned)lo16)<<(16*(r-2)); }
      }
      int cs = co ^ ((l&7)<<4);
      *(uint2*)((char*)xnh + (size_t)b*BST + (size_t)l*128 + cs) = make_uint2(h0,h1);
      *(uint2*)((char*)xnl + (size_t)b*BST + (size_t)l*128 + cs) = make_uint2(lo0,lo1);
    }
  } else {
    #pragma unroll
    for (int ls=0;ls<8;ls++){
      int l = l0 + ls*16 + lr;
      if (l < LL){
        #pragma unroll
        for (int r=0;r<4;r++){
          int o = os*16 + 4*q + r;
          dout[((size_t)(b*64 + o))*LL + l] = acc[ls][r] + bias[r];
        }
      }
    }
  }
}

extern "C" void kernel_launch(void* const* d_in, const int* in_sizes, int n_in,
                              void* d_out, int out_size, void* d_ws, size_t ws_size,
                              hipStream_t stream) {
  const float* x   = (const float*)d_in[0];
  const float* lw  = (const float*)d_in[1];
  const float* lb  = (const float*)d_in[2];
  const float* cw  = (const float*)d_in[3];
  const float* cb  = (const float*)d_in[4];
  const float* swr = (const float*)d_in[5];
  const float* swi = (const float*)d_in[6];

  char* ws = (char*)d_ws;
  size_t PL = (size_t)NB*BST;                 // 34,603,008 bytes per plane
  unsigned short* xlc0h = (unsigned short*)(ws);
  unsigned short* xlc0l = (unsigned short*)(ws + PL);
  unsigned short* xlc1h = (unsigned short*)(ws + 2*PL);
  unsigned short* xlc1l = (unsigned short*)(ws + 3*PL);
  unsigned short* tf    = (unsigned short*)(ws + 4*PL);
  unsigned short* tif   = (unsigned short*)(ws + 4*PL + 540672);
  unsigned short* wfch  = (unsigned short*)(ws + 4*PL + 2*540672);
  unsigned short* wfcl  = (unsigned short*)(ws + 4*PL + 2*540672 + 32768);
  unsigned short* wmh   = (unsigned short*)(ws + 4*PL + 2*540672 + 2*32768);
  unsigned short* wml   = (unsigned short*)(ws + 4*PL + 2*540672 + 2*32768 + 524288);
  float*          xm    = (float*)        (ws + 4*PL + 2*540672 + 2*32768 + 2*524288);

  k_tf  <<<1056,256,0,stream>>>(tf);
  k_tif <<<1056,256,0,stream>>>(tif);
  k_wfc <<<64,  256,0,stream>>>(cw, wfch, wfcl);
  k_lift<<<1056,256,0,stream>>>(x, lw, lb, xlc0h, xlc0l);

  for (int k=0;k<NRL;k++){
    unsigned short* curh = (k&1) ? xlc1h : xlc0h;
    unsigned short* curl = (k&1) ? xlc1l : xlc0l;
    unsigned short* nxth = (k&1) ? xlc0h : xlc1h;
    unsigned short* nxtl = (k&1) ? xlc0l : xlc1l;
    float* xmp = (float*)nxth;   // 12.6MB scratch, consumed before k_layer overwrites
    k_dft<<<dim3(DCH,NB),256,0,stream>>>(curh, tf, xmp);
    k_red<<<1024,256,0,stream>>>(xmp, xm);
    k_mix<<<512, 256,0,stream>>>(xm, swr + (size_t)k*131072, swi + (size_t)k*131072, wmh, wml);
    k_layer<<<dim3(33,NB),256,0,stream>>>(curh, curl,
        wfch + (size_t)k*4096, wfcl + (size_t)k*4096, wmh, wml, tif,
        cb + (size_t)k*64, nxth, nxtl, (float*)d_out, (k==NRL-1) ? 1 : 0);
  }
}

// Round 4
// 305.593 us; speedup vs baseline: 3.5794x; 1.1973x over previous
//
#include <hip/hip_runtime.h>
#include <hip/hip_bf16.h>
#include <math.h>

#define NRL 4
#define LL 4096
#define NFFT 4104
#define LP 4224
#define NB 64
#define WD 64
#define BST (LP*WD*2)        // 540672 bytes per batch: [l][c] bf16 plane, or [c][l] plane
#define DCH 12
#define DKS 11
#define PI2 6.28318530717958647692f

typedef __attribute__((ext_vector_type(8))) short short8;
typedef __attribute__((ext_vector_type(4))) float f32x4;

__device__ inline unsigned short f2bf(float f){
  unsigned int u = __float_as_uint(f);
  return (unsigned short)((u + 0x7FFFu + ((u>>16)&1u)) >> 16);
}
__device__ inline float gelu_f(float v){
  return 0.5f*v*(1.0f + erff(v*0.70710678118654752440f));
}

// ---- forward-DFT B-operand table, fragment order: tf[ks 132][js 4][lane 64][e 8]
__global__ void k_tf(unsigned short* __restrict__ tf){
  int idx = blockIdx.x*256 + threadIdx.x;     // 270336
  int e = idx & 7; int t = idx >> 3;
  int lane = t & 63; int t2 = t >> 6;
  int js = t2 & 3; int ks = t2 >> 2;
  int l = ks*32 + 8*(lane>>4) + e;
  int j = js*16 + (lane & 15);
  int m = j >> 1;
  float v = 0.f;
  if (l < NFFT){
    int r = (m*l) % NFFT;
    float ang = PI2 * ((float)r / (float)NFFT);
    v = (j & 1) ? -sinf(ang) : cosf(ang);
  }
  tf[idx] = f2bf(v);
}

// ---- inverse-spectral B-operand table: tif[(ks2*4+q)*LP + l][e 8]
__global__ void k_tif(unsigned short* __restrict__ tif){
  int idx = blockIdx.x*256 + threadIdx.x;     // 270336
  int e = idx & 7; int t = idx >> 3;
  int l = t % LP; int rq = t / LP;
  int q = rq & 3; int ks2 = rq >> 2;
  int j2 = ks2*32 + 8*q + e;
  int m = j2 >> 1;
  float v = 0.f;
  if (l < NFFT){
    int r = (m*l) % NFFT;
    float ang = PI2 * ((float)r / (float)NFFT);
    float inv = 1.0f/(float)NFFT;
    v = (j2 & 1) ? (-2.f*inv*sinf(ang)) : ((m==0?inv:2.f*inv)*cosf(ang));
  }
  tif[idx] = f2bf(v);
}

// ---- conv-weight A-operand frags: [layer 4][ks2 2][os 4][lane 64][e 8] hi/lo
__global__ void k_wfc(const float* __restrict__ cw,
                      unsigned short* __restrict__ whi, unsigned short* __restrict__ wlo){
  int idx = blockIdx.x*256 + threadIdx.x;     // 16384
  int e = idx & 7; int lane = (idx>>3)&63; int os = (idx>>9)&3;
  int ks2 = (idx>>11)&1; int ly = idx>>12;
  int k = ks2*32 + 8*(lane>>4) + e;
  int o = os*16 + (lane&15);
  float v = cw[((size_t)(ly*64 + o))*64 + k];
  unsigned short h = f2bf(v);
  float lo = v - __uint_as_float(((unsigned)h)<<16);
  whi[idx] = h; wlo[idx] = f2bf(lo);
}

// ---- lift into [l][c] swizzled plane; 8 threads cooperate per l-row (coalesced)
__global__ void k_lift_lc(const float* __restrict__ x, const float* __restrict__ lw,
                          const float* __restrict__ lb, unsigned short* __restrict__ xh){
  int idx = blockIdx.x*256 + threadIdx.x;     // 2162688 = 64*4224*8
  int u = idx & 7; int t = idx >> 3;
  int l = t % LP; int b = t / LP;
  char* ph = (char*)xh + (size_t)b*BST + (size_t)l*128;
  int sw = (l & 7) << 4;
  if (l >= LL){
    *(uint4*)(ph + ((u*16)^sw)) = make_uint4(0,0,0,0);
    return;
  }
  float xv = x[(size_t)b*LL + l];
  float g = (float)l * (1.0f/4095.0f);
  unsigned int w_[4];
  #pragma unroll
  for (int p=0;p<4;p++){
    unsigned int hh=0;
    #pragma unroll
    for (int s=0;s<2;s++){
      int c = u*8 + p*2 + s;
      float v = fmaf(lw[2*c], xv, fmaf(lw[2*c+1], g, lb[c]));
      hh |= ((unsigned)f2bf(v)) << (16*s);
    }
    w_[p]=hh;
  }
  *(uint4*)(ph + ((u*16)^sw)) = make_uint4(w_[0],w_[1],w_[2],w_[3]);
}

// ---- lift into transposed [c][l] plane; thread = (b,c,l8), 8 l's -> one 16B store
__global__ void k_lift_t(const float* __restrict__ x, const float* __restrict__ lw,
                         const float* __restrict__ lb, unsigned short* __restrict__ xt){
  int idx = blockIdx.x*256 + threadIdx.x;     // 2162688 = 64*64*528
  int l8 = idx % 528; int t = idx / 528;
  int c = t & 63; int b = t >> 6;
  int l = l8*8;
  short8 v8;
  if (l8 >= 512){
    #pragma unroll
    for (int s=0;s<8;s++) v8[s] = 0;
  } else {
    float4 x0 = *reinterpret_cast<const float4*>(x + (size_t)b*LL + l);
    float4 x1 = *reinterpret_cast<const float4*>(x + (size_t)b*LL + l + 4);
    float w0 = lw[2*c], w1 = lw[2*c+1], bb = lb[c];
    const float gs = 1.0f/4095.0f;
    float xs[8] = {x0.x,x0.y,x0.z,x0.w,x1.x,x1.y,x1.z,x1.w};
    #pragma unroll
    for (int s=0;s<8;s++){
      float v = fmaf(w0, xs[s], fmaf(w1, (float)(l+s)*gs, bb));
      v8[s] = (short)f2bf(v);
    }
  }
  *(short8*)(xt + ((size_t)b*64 + c)*LP + l) = v8;
}

// ---- forward DFT via MFMA reading transposed x: D[c][j] partials per (chunk,b)
__global__ __launch_bounds__(256) void k_dft(const unsigned short* __restrict__ xt,
    const unsigned short* __restrict__ tf, float* __restrict__ xmp){
  int ch = blockIdx.x; int b = blockIdx.y;
  int w = threadIdx.x >> 6; int lane = threadIdx.x & 63;
  int q = lane >> 4; int lr = lane & 15;
  const unsigned short* xrow = xt + ((size_t)b*64 + w*16 + lr)*LP;
  f32x4 acc[4];
  #pragma unroll
  for (int js=0;js<4;js++) acc[js] = (f32x4){0.f,0.f,0.f,0.f};
  for (int ksl=0; ksl<DKS; ksl++){
    int ks = ch*DKS + ksl;
    short8 av = *(const short8*)(xrow + ks*32 + 8*q);
    #pragma unroll
    for (int js=0;js<4;js++){
      short8 bv = *(const short8*)(tf + ((size_t)((ks*4+js)*64 + lane))*8);
      acc[js] = __builtin_amdgcn_mfma_f32_16x16x32_bf16(av, bv, acc[js], 0,0,0);
    }
  }
  #pragma unroll
  for (int js=0;js<4;js++){
    #pragma unroll
    for (int r=0;r<4;r++)
      xmp[(size_t)ch*262144 + ((size_t)(b*64 + w*16 + 4*q + r))*64 + js*16 + lr] = acc[js][r];
  }
}

__global__ void k_red(const float* __restrict__ xmp, float* __restrict__ xm){
  int i = blockIdx.x*256 + threadIdx.x;       // 262144
  float s = 0.f;
  #pragma unroll
  for (int p=0;p<DCH;p++) s += xmp[(size_t)p*262144 + i];
  xm[i] = s;
}

// ---- mode mix -> om A-operand frags [b][ks2 2][os 4][lane 64][e 8] hi/lo
__global__ void k_mix(const float* __restrict__ xm, const float* __restrict__ wr,
                      const float* __restrict__ wi,
                      unsigned short* __restrict__ mh, unsigned short* __restrict__ ml){
  int idx = blockIdx.x*256 + threadIdx.x;     // 131072
  int m = idx & 31, o = (idx>>5)&63, b = idx>>11;
  const float* xp = xm + ((size_t)(b*64))*64 + 2*m;
  float ar=0.f, ai=0.f;
  for (int i=0;i<64;i++){
    float xr = xp[i*64], xi = xp[i*64+1];
    float wrv = wr[((size_t)(i*64 + o))*32 + m];
    float wiv = wi[((size_t)(i*64 + o))*32 + m];
    ar = fmaf(xr,wrv,ar); ar = fmaf(-xi,wiv,ar);
    ai = fmaf(xr,wiv,ai); ai = fmaf(xi,wrv,ai);
  }
  int j2 = 2*m;
  int ks2 = j2 >> 5, rem = j2 & 31, q = rem >> 3, e = rem & 7;
  int lane = q*16 + (o & 15), os = o >> 4;
  size_t a = ((size_t)(((b*2 + ks2)*4 + os)*64 + lane))*8 + e;
  unsigned short hr = f2bf(ar), hi_ = f2bf(ai);
  float lr_ = ar - __uint_as_float(((unsigned)hr)<<16);
  float li_ = ai - __uint_as_float(((unsigned)hi_)<<16);
  *(ushort2*)(mh + a) = make_ushort2(hr, hi_);
  *(ushort2*)(ml + a) = make_ushort2(f2bf(lr_), f2bf(li_));
}

// ---- fused layer: no LDS, B-frags read straight from L2/L3
__global__ __launch_bounds__(256) void k_layer(
    const unsigned short* __restrict__ xlc,
    const unsigned short* __restrict__ wfch, const unsigned short* __restrict__ wfcl,
    const unsigned short* __restrict__ wmh, const unsigned short* __restrict__ wml,
    const unsigned short* __restrict__ tif, const float* __restrict__ cb,
    unsigned short* __restrict__ xnh, unsigned short* __restrict__ xnt,
    float* __restrict__ dout, int last){
  int l0 = blockIdx.x * 128; int b = blockIdx.y;
  int tid = threadIdx.x;
  int os = tid >> 6, lane = tid & 63, q = lane >> 4, lr = lane & 15;
  const char* xb = (const char*)xlc + (size_t)b*BST;

  short8 ch_[2], cl_[2], mh_[2], ml_[2];
  #pragma unroll
  for (int ks=0;ks<2;ks++){
    size_t a = ((size_t)((ks*4 + os)*64 + lane))*8;
    ch_[ks] = *(const short8*)(wfch + a);
    cl_[ks] = *(const short8*)(wfcl + a);
    size_t am = ((size_t)(((b*2 + ks)*4 + os)*64 + lane))*8;
    mh_[ks] = *(const short8*)(wmh + am);
    ml_[ks] = *(const short8*)(wml + am);
  }
  f32x4 acc[8];
  #pragma unroll
  for (int ls=0;ls<8;ls++) acc[ls] = (f32x4){0.f,0.f,0.f,0.f};
  int sw = (lr & 7) << 4;
  #pragma unroll
  for (int ks=0;ks<2;ks++){
    int cofs = (64*ks + 16*q) ^ sw;
    #pragma unroll
    for (int ls=0;ls<8;ls++){
      short8 bh = *(const short8*)(xb + (size_t)(l0 + ls*16 + lr)*128 + cofs);
      acc[ls] = __builtin_amdgcn_mfma_f32_16x16x32_bf16(ch_[ks], bh, acc[ls], 0,0,0);
      acc[ls] = __builtin_amdgcn_mfma_f32_16x16x32_bf16(cl_[ks], bh, acc[ls], 0,0,0);
    }
  }
  #pragma unroll
  for (int ks=0;ks<2;ks++){
    #pragma unroll
    for (int ls=0;ls<8;ls++){
      int l = l0 + ls*16 + lr;
      short8 bt = *(const short8*)(tif + ((size_t)((ks*4 + q)*LP + l))*8);
      acc[ls] = __builtin_amdgcn_mfma_f32_16x16x32_bf16(mh_[ks], bt, acc[ls], 0,0,0);
      acc[ls] = __builtin_amdgcn_mfma_f32_16x16x32_bf16(ml_[ks], bt, acc[ls], 0,0,0);
    }
  }
  float bias[4];
  #pragma unroll
  for (int r=0;r<4;r++) bias[r] = cb[os*16 + 4*q + r];
  if (!last){
    int co = os*32 + 8*q;
    char* nb = (char*)xnh + (size_t)b*BST;
    unsigned short* tb = xnt + (size_t)b*64*LP;
    #pragma unroll
    for (int ls=0;ls<8;ls++){
      int l = l0 + ls*16 + lr;
      unsigned short us[4];
      #pragma unroll
      for (int r=0;r<4;r++) us[r] = f2bf(gelu_f(acc[ls][r] + bias[r]));
      unsigned int h0 = (unsigned)us[0] | (((unsigned)us[1])<<16);
      unsigned int h1 = (unsigned)us[2] | (((unsigned)us[3])<<16);
      *(uint2*)(nb + (size_t)l*128 + (co ^ sw)) = make_uint2(h0,h1);
      #pragma unroll
      for (int r=0;r<4;r++) tb[(size_t)(os*16 + 4*q + r)*LP + l] = us[r];
    }
  } else {
    #pragma unroll
    for (int ls=0;ls<8;ls++){
      int l = l0 + ls*16 + lr;
      if (l < LL){
        #pragma unroll
        for (int r=0;r<4;r++){
          int o = os*16 + 4*q + r;
          dout[((size_t)(b*64 + o))*LL + l] = acc[ls][r] + bias[r];
        }
      }
    }
  }
}

extern "C" void kernel_launch(void* const* d_in, const int* in_sizes, int n_in,
                              void* d_out, int out_size, void* d_ws, size_t ws_size,
                              hipStream_t stream) {
  const float* x   = (const float*)d_in[0];
  const float* lw  = (const float*)d_in[1];
  const float* lb  = (const float*)d_in[2];
  const float* cw  = (const float*)d_in[3];
  const float* cb  = (const float*)d_in[4];
  const float* swr = (const float*)d_in[5];
  const float* swi = (const float*)d_in[6];

  char* ws = (char*)d_ws;
  size_t PL = (size_t)NB*BST;                 // 34,603,008 bytes per plane
  unsigned short* x0lc = (unsigned short*)(ws);
  unsigned short* x0t  = (unsigned short*)(ws + PL);
  unsigned short* x1lc = (unsigned short*)(ws + 2*PL);
  unsigned short* x1t  = (unsigned short*)(ws + 3*PL);
  unsigned short* tf   = (unsigned short*)(ws + 4*PL);
  unsigned short* tif  = (unsigned short*)(ws + 4*PL + 540672);
  unsigned short* wfch = (unsigned short*)(ws + 4*PL + 2*540672);
  unsigned short* wfcl = (unsigned short*)(ws + 4*PL + 2*540672 + 32768);
  unsigned short* wmh  = (unsigned short*)(ws + 4*PL + 2*540672 + 2*32768);
  unsigned short* wml  = (unsigned short*)(ws + 4*PL + 2*540672 + 2*32768 + 524288);
  float*          xm   = (float*)        (ws + 4*PL + 2*540672 + 2*32768 + 2*524288);

  k_tf     <<<1056,256,0,stream>>>(tf);
  k_tif    <<<1056,256,0,stream>>>(tif);
  k_wfc    <<<64,  256,0,stream>>>(cw, wfch, wfcl);
  k_lift_lc<<<8448,256,0,stream>>>(x, lw, lb, x0lc);
  k_lift_t <<<8448,256,0,stream>>>(x, lw, lb, x0t);

  for (int k=0;k<NRL;k++){
    unsigned short* curlc = (k&1) ? x1lc : x0lc;
    unsigned short* curt  = (k&1) ? x1t  : x0t;
    unsigned short* nxtlc = (k&1) ? x0lc : x1lc;
    unsigned short* nxtt  = (k&1) ? x0t  : x1t;
    float* xmp = (float*)nxtlc;   // 12.6MB scratch, consumed by k_red before k_layer overwrites
    k_dft<<<dim3(DCH,NB),256,0,stream>>>(curt, tf, xmp);
    k_red<<<1024,256,0,stream>>>(xmp, xm);
    k_mix<<<512, 256,0,stream>>>(xm, swr + (size_t)k*131072, swi + (size_t)k*131072, wmh, wml);
    k_layer<<<dim3(33,NB),256,0,stream>>>(curlc,
        wfch + (size_t)k*4096, wfcl + (size_t)k*4096, wmh, wml, tif,
        cb + (size_t)k*64, nxtlc, nxtt, (float*)d_out, (k==NRL-1) ? 1 : 0);
  }
}